// Round 1
// baseline (9236.201 us; speedup 1.0000x reference)
//
#include <hip/hip_runtime.h>
#include <cstddef>
#include <cstdint>
#include <math.h>

#define BB 64
#define PP 196
#define ENCD 512
#define DECD 512
#define ATTD 512
#define VOC 10000
#define CLSE 512
#define MAXLEN 52
#define MAXT 51
#define G4 2048
#define XDIM 1536

// ---- d_out offsets (float elements) ----
#define OFF_PRED 0
#define OFF_CAPS (BB * MAXT * VOC)          // 32640000
#define OFF_DECLEN (OFF_CAPS + BB * MAXLEN) // +3328
#define OFF_SORT (OFF_DECLEN + BB)

// ---- workspace offsets (4-byte units) ----
static constexpr size_t W_SORT   = 0;                       // int[64]
static constexpr size_t W_DECLEN = 64;                      // int[64]
static constexpr size_t W_CAPS   = 128;                     // int[64*52]
static constexpr size_t W_CLS    = 3584;                    // f32[64*512] cls_emb (UNSORTED rows, reference quirk)
static constexpr size_t W_H      = W_CLS + BB * CLSE;
static constexpr size_t W_C      = W_H + BB * DECD;
static constexpr size_t W_ININ   = W_C + BB * DECD;         // f32[64*1024]
static constexpr size_t W_Z      = W_ININ + BB * 1024;      // f32[64*3072]  att2|gate_pre|hh
static constexpr size_t W_AWE    = W_Z + BB * 3072;         // f32[64*512]
static constexpr size_t W_GATES  = W_AWE + BB * ENCD;       // f32[64*2048]
static constexpr size_t W_CLSPRE = W_GATES + BB * G4;       // f32[64*2048]
static constexpr size_t W_W1     = W_CLSPRE + BB * G4;      // f32[512*3072] [dec_att_W | f_beta_W | Whh^T]
static constexpr size_t W_W2     = W_W1 + (size_t)512 * 3072;   // f32[1024*2048] Wih[:, :1024]^T
static constexpr size_t W_HALL   = W_W2 + (size_t)1024 * G4;    // f32[64*51*512]
static constexpr size_t W_ATT1   = W_HALL + (size_t)BB * MAXT * DECD; // f32[64*196*512]

__device__ __forceinline__ float sigm(float x) { return 1.f / (1.f + expf(-x)); }

// ---------------- setup: stable descending argsort of lengths ----------------
__global__ void setup_kernel(const int* __restrict__ cap_len, float* __restrict__ out,
                             int* __restrict__ sortind, int* __restrict__ declen) {
    __shared__ int sl[BB];
    int i = threadIdx.x; // 0..63
    sl[i] = cap_len[i];
    __syncthreads();
    int li = sl[i];
    int rank = 0;
    for (int j = 0; j < BB; j++) {
        int lj = sl[j];
        rank += (lj > li) || (lj == li && j < i); // stable descending
    }
    sortind[rank] = i;
    declen[rank] = li - 1;
    out[OFF_SORT + rank] = (float)i;
    out[OFF_DECLEN + rank] = (float)(li - 1);
}

// ---------------- gather caps (sorted) + cls_emb (UNSORTED) ----------------
__global__ void gather_kernel(const int* __restrict__ ecaps, const int* __restrict__ classk,
                              const float* __restrict__ clsW, const int* __restrict__ sortind,
                              int* __restrict__ caps_i, float* __restrict__ cls,
                              float* __restrict__ out) {
    int idx = blockIdx.x * 256 + threadIdx.x;
    if (idx < BB * MAXLEN) {
        int b = idx / MAXLEN, t2 = idx - b * MAXLEN;
        int sb = sortind[b];
        int v = ecaps[sb * MAXLEN + t2];
        caps_i[idx] = v;
        out[OFF_CAPS + idx] = (float)v;
    }
    int j = idx - BB * MAXLEN;
    if (j >= 0 && j < BB * CLSE) {
        int row = j >> 9, k = j & 511;
        int ck = classk[row]; // NOT sorted — matches reference
        cls[j] = clsW[ck * CLSE + k];
    }
}

// ---------------- mean over P + build init_in ----------------
__global__ void mean_cls_kernel(const float* __restrict__ enc, const float* __restrict__ cls,
                                const int* __restrict__ sortind, float* __restrict__ initin) {
    int b = blockIdx.x;
    int sb = sortind[b];
    for (int k = threadIdx.x; k < ENCD; k += 256) {
        const float* ep = enc + (size_t)sb * PP * ENCD + k;
        float s = 0.f;
        for (int p = 0; p < PP; p++) s += ep[(size_t)p * ENCD];
        initin[b * 1024 + k] = s * (1.f / 196.f);
        initin[b * 1024 + 512 + k] = cls[b * CLSE + k];
    }
}

// ---------------- h0 / c0 ----------------
__global__ void init_hc_kernel(const float* __restrict__ initin,
                               const float* __restrict__ hW, const float* __restrict__ hb,
                               const float* __restrict__ cW, const float* __restrict__ cb,
                               float* __restrict__ h, float* __restrict__ c) {
    int gid = blockIdx.x * 256 + threadIdx.x; // < 65536
    int j = gid & 511, b = (gid >> 9) & 63, which = gid >> 15;
    const float* W = which ? cW : hW;
    const float* bias = which ? cb : hb;
    const float* x = initin + b * 1024;
    float acc = bias[j];
    for (int k = 0; k < 1024; k++) acc += x[k] * W[(size_t)k * 512 + j];
    (which ? c : h)[b * 512 + j] = acc;
}

// ---------------- weight packing ----------------
__global__ void pack_w1_kernel(const float* __restrict__ dA, const float* __restrict__ fB,
                               const float* __restrict__ whh, float* __restrict__ W1) {
    int idx = blockIdx.x * 256 + threadIdx.x; // < 512*3072
    int d = idx / 3072, q = idx - d * 3072;
    float v;
    if (q < 512) v = dA[d * 512 + q];
    else if (q < 1024) v = fB[d * 512 + (q - 512)];
    else v = whh[(size_t)(q - 1024) * 512 + d];
    W1[idx] = v;
}

__global__ void pack_w2_kernel(const float* __restrict__ wih, float* __restrict__ W2) {
    int idx = blockIdx.x * 256 + threadIdx.x; // < 1024*2048
    int k = idx >> 11, j = idx & 2047;
    W2[idx] = wih[(size_t)j * XDIM + k];
}

// ---------------- att1 = enc_sorted @ enc_att_W + b : 12544x512, K=512 ----------------
__global__ __launch_bounds__(256)
void att1_kernel(const float* __restrict__ enc, const float* __restrict__ Wa,
                 const float* __restrict__ ba, const int* __restrict__ sortind,
                 float* __restrict__ att1) {
    __shared__ float As[16][66];
    __shared__ float Bs[16][64];
    int tid = threadIdx.x;
    int n0 = blockIdx.x * 64, m0 = blockIdx.y * 64;
    int tx = tid & 15, ty = tid >> 4;
    int lm = tid >> 2, lk4 = (tid & 3) * 4;
    int bkk = tid >> 4, bnn4 = (tid & 15) * 4;
    int gm = m0 + lm;
    int b = gm / PP, p = gm - b * PP;
    int sb = sortind[b];
    const float* arow = enc + ((size_t)sb * PP + p) * ENCD;
    float acc[4][4] = {};
    for (int k0 = 0; k0 < ENCD; k0 += 16) {
        float4 av = *(const float4*)(arow + k0 + lk4);
        float4 bv = *(const float4*)(Wa + (size_t)(k0 + bkk) * 512 + n0 + bnn4);
        __syncthreads();
        As[lk4 + 0][lm] = av.x; As[lk4 + 1][lm] = av.y;
        As[lk4 + 2][lm] = av.z; As[lk4 + 3][lm] = av.w;
        *(float4*)&Bs[bkk][bnn4] = bv;
        __syncthreads();
#pragma unroll
        for (int kk = 0; kk < 16; kk++) {
            float a[4], bq[4];
#pragma unroll
            for (int i = 0; i < 4; i++) a[i] = As[kk][ty * 4 + i];
#pragma unroll
            for (int jj = 0; jj < 4; jj++) bq[jj] = Bs[kk][tx * 4 + jj];
#pragma unroll
            for (int i = 0; i < 4; i++)
#pragma unroll
                for (int jj = 0; jj < 4; jj++) acc[i][jj] += a[i] * bq[jj];
        }
    }
#pragma unroll
    for (int i = 0; i < 4; i++) {
        int m = m0 + ty * 4 + i;
        int n = n0 + tx * 4;
        float4 o;
        o.x = acc[i][0] + ba[n + 0];
        o.y = acc[i][1] + ba[n + 1];
        o.z = acc[i][2] + ba[n + 2];
        o.w = acc[i][3] + ba[n + 3];
        *(float4*)(att1 + (size_t)m * ATTD + n) = o;
    }
}

// ---------------- clspre = cls @ Wih[:,1024:1536]^T + bih + bhh : 64x2048 ----------------
__global__ __launch_bounds__(256)
void clspre_kernel(const float* __restrict__ cls, const float* __restrict__ wih,
                   const float* __restrict__ bih, const float* __restrict__ bhh,
                   float* __restrict__ clspre) {
    __shared__ float As[16][66];
    __shared__ float Bs[16][68];
    int tid = threadIdx.x;
    int n0 = blockIdx.x * 64;
    int tx = tid & 15, ty = tid >> 4;
    int lm = tid >> 2, lk4 = (tid & 3) * 4;
    int bnn = tid & 63, bkk4 = (tid >> 6) * 4;
    float acc[4][4] = {};
    for (int k0 = 0; k0 < 512; k0 += 16) {
        float4 av = *(const float4*)(cls + lm * CLSE + k0 + lk4);
        float4 bv = *(const float4*)(wih + (size_t)(n0 + bnn) * XDIM + 1024 + k0 + bkk4);
        __syncthreads();
        As[lk4 + 0][lm] = av.x; As[lk4 + 1][lm] = av.y;
        As[lk4 + 2][lm] = av.z; As[lk4 + 3][lm] = av.w;
        Bs[bkk4 + 0][bnn] = bv.x; Bs[bkk4 + 1][bnn] = bv.y;
        Bs[bkk4 + 2][bnn] = bv.z; Bs[bkk4 + 3][bnn] = bv.w;
        __syncthreads();
#pragma unroll
        for (int kk = 0; kk < 16; kk++) {
            float a[4], bq[4];
#pragma unroll
            for (int i = 0; i < 4; i++) a[i] = As[kk][ty * 4 + i];
#pragma unroll
            for (int jj = 0; jj < 4; jj++) bq[jj] = Bs[kk][tx * 4 + jj];
#pragma unroll
            for (int i = 0; i < 4; i++)
#pragma unroll
                for (int jj = 0; jj < 4; jj++) acc[i][jj] += a[i] * bq[jj];
        }
    }
#pragma unroll
    for (int i = 0; i < 4; i++) {
        int m = ty * 4 + i;
#pragma unroll
        for (int jj = 0; jj < 4; jj++) {
            int n = n0 + tx * 4 + jj;
            clspre[m * G4 + n] = acc[i][jj] + bih[n] + bhh[n];
        }
    }
}

// ---------------- S1: Z = h @ [dec_att|f_beta|Whh^T] (+biases) : 64x3072, K=512 ----------------
__global__ __launch_bounds__(1024)
void s1_kernel(const float* __restrict__ h, const float* __restrict__ W1,
               const float* __restrict__ dab, const float* __restrict__ fbb,
               float* __restrict__ Z) {
    __shared__ float As[16][66];
    __shared__ float Bs[16][64];
    int tid = threadIdx.x;
    int n0 = blockIdx.x * 64;
    int tx = tid & 31, ty = tid >> 5;
    int alm = tid >> 4, alk = tid & 15;
    int bkk = tid >> 6, bnn = tid & 63;
    float acc00 = 0, acc01 = 0, acc10 = 0, acc11 = 0;
    for (int k0 = 0; k0 < 512; k0 += 16) {
        float a = h[alm * DECD + k0 + alk];
        float bv = W1[(size_t)(k0 + bkk) * 3072 + n0 + bnn];
        __syncthreads();
        As[alk][alm] = a;
        Bs[bkk][bnn] = bv;
        __syncthreads();
#pragma unroll
        for (int kk = 0; kk < 16; kk++) {
            float2 a2 = *(const float2*)&As[kk][ty * 2];
            float2 b2 = *(const float2*)&Bs[kk][tx * 2];
            acc00 += a2.x * b2.x; acc01 += a2.x * b2.y;
            acc10 += a2.y * b2.x; acc11 += a2.y * b2.y;
        }
    }
    int m = ty * 2, n = n0 + tx * 2;
    float bias0 = (n < 512) ? dab[n] : ((n < 1024) ? fbb[n - 512] : 0.f);
    int n1 = n + 1;
    float bias1 = (n1 < 512) ? dab[n1] : ((n1 < 1024) ? fbb[n1 - 512] : 0.f);
    Z[m * 3072 + n] = acc00 + bias0;
    Z[m * 3072 + n1] = acc01 + bias1;
    Z[(m + 1) * 3072 + n] = acc10 + bias0;
    Z[(m + 1) * 3072 + n1] = acc11 + bias1;
}

// ---------------- S2: attention per batch row ----------------
__global__ __launch_bounds__(256)
void s2_kernel(const float* __restrict__ att1, const float* __restrict__ Z,
               const float* __restrict__ enc, const float* __restrict__ fullw,
               const float* __restrict__ fullb, const int* __restrict__ sortind,
               const int* __restrict__ declen, float* __restrict__ awe, int t) {
    int b = blockIdx.x;
    if (t >= declen[b]) return; // frozen row
    __shared__ float att2s[ATTD];
    __shared__ float wv[ATTD];
    __shared__ float es[PP];
    __shared__ float red[8];
    int tid = threadIdx.x;
    for (int k = tid; k < ATTD; k += 256) {
        att2s[k] = Z[b * 3072 + k];
        wv[k] = fullw[k];
    }
    __syncthreads();
    int lane = tid & 63, wid = tid >> 6;
    float fb = fullb[0];
    for (int p = wid; p < PP; p += 4) {
        const float* ar = att1 + ((size_t)(b * PP + p)) * ATTD;
        float s = 0.f;
        for (int a = lane; a < ATTD; a += 64) {
            float v = ar[a] + att2s[a];
            s += fmaxf(v, 0.f) * wv[a];
        }
#pragma unroll
        for (int off = 32; off; off >>= 1) s += __shfl_down(s, off, 64);
        if (lane == 0) es[p] = s + fb;
    }
    __syncthreads();
    float m = -1e30f;
    for (int p = tid; p < PP; p += 256) m = fmaxf(m, es[p]);
#pragma unroll
    for (int off = 32; off; off >>= 1) m = fmaxf(m, __shfl_down(m, off, 64));
    if (lane == 0) red[wid] = m;
    __syncthreads();
    m = fmaxf(fmaxf(red[0], red[1]), fmaxf(red[2], red[3]));
    float ls = 0.f;
    for (int p = tid; p < PP; p += 256) {
        float ev = expf(es[p] - m);
        es[p] = ev;
        ls += ev;
    }
#pragma unroll
    for (int off = 32; off; off >>= 1) ls += __shfl_down(ls, off, 64);
    __syncthreads();
    if (lane == 0) red[4 + wid] = ls;
    __syncthreads();
    float inv = 1.f / (red[4] + red[5] + red[6] + red[7]);
    int sb = sortind[b];
    for (int k = tid; k < ENCD; k += 256) {
        const float* ep = enc + (size_t)sb * PP * ENCD + k;
        float acc = 0.f;
        for (int p = 0; p < PP; p++) acc += es[p] * ep[(size_t)p * ENCD];
        float g = sigm(Z[b * 3072 + 512 + k]);
        awe[b * ENCD + k] = acc * inv * g;
    }
}

// ---------------- S3: gates = [emb_t|awe]@W2 + clspre + hh : 64x2048, K=1024 ----------------
__global__ __launch_bounds__(1024)
void s3_kernel(const float* __restrict__ embW, const float* __restrict__ awe,
               const float* __restrict__ W2, const float* __restrict__ clspre,
               const float* __restrict__ Z, const int* __restrict__ caps_i,
               float* __restrict__ gates, int t) {
    __shared__ float As[16][66];
    __shared__ float Bs[16][64];
    __shared__ int capRow[64];
    int tid = threadIdx.x;
    if (tid < 64) capRow[tid] = caps_i[tid * MAXLEN + t];
    __syncthreads();
    int n0 = blockIdx.x * 64;
    int tx = tid & 31, ty = tid >> 5;
    int alm = tid >> 4, alk = tid & 15;
    int bkk = tid >> 6, bnn = tid & 63;
    int cap = capRow[alm];
    const float* embrow = embW + (size_t)cap * 512;
    const float* awerow = awe + alm * 512;
    float acc00 = 0, acc01 = 0, acc10 = 0, acc11 = 0;
    for (int k0 = 0; k0 < 1024; k0 += 16) {
        int k = k0 + alk;
        float a = (k < 512) ? embrow[k] : awerow[k - 512];
        float bv = W2[(size_t)(k0 + bkk) * G4 + n0 + bnn];
        __syncthreads();
        As[alk][alm] = a;
        Bs[bkk][bnn] = bv;
        __syncthreads();
#pragma unroll
        for (int kk = 0; kk < 16; kk++) {
            float2 a2 = *(const float2*)&As[kk][ty * 2];
            float2 b2 = *(const float2*)&Bs[kk][tx * 2];
            acc00 += a2.x * b2.x; acc01 += a2.x * b2.y;
            acc10 += a2.y * b2.x; acc11 += a2.y * b2.y;
        }
    }
    int m = ty * 2, n = n0 + tx * 2;
    gates[m * G4 + n]           = acc00 + clspre[m * G4 + n]           + Z[m * 3072 + 1024 + n];
    gates[m * G4 + n + 1]       = acc01 + clspre[m * G4 + n + 1]       + Z[m * 3072 + 1024 + n + 1];
    gates[(m + 1) * G4 + n]     = acc10 + clspre[(m + 1) * G4 + n]     + Z[(m + 1) * 3072 + 1024 + n];
    gates[(m + 1) * G4 + n + 1] = acc11 + clspre[(m + 1) * G4 + n + 1] + Z[(m + 1) * 3072 + 1024 + n + 1];
}

// ---------------- S4: LSTM pointwise update ----------------
__global__ void s4_kernel(const float* __restrict__ gates, float* __restrict__ h,
                          float* __restrict__ c, float* __restrict__ hall,
                          const int* __restrict__ declen, int t) {
    int gid = blockIdx.x * 256 + threadIdx.x; // < 64*512
    int b = gid >> 9, d = gid & 511;
    if (t >= declen[b]) return;
    const float* gb = gates + b * G4;
    float i_ = gb[d], f_ = gb[512 + d], g_ = gb[1024 + d], o_ = gb[1536 + d];
    float cn = sigm(f_) * c[gid] + sigm(i_) * tanhf(g_);
    float hn = sigm(o_) * tanhf(cn);
    c[gid] = cn;
    h[gid] = hn;
    hall[((size_t)b * MAXT + t) * DECD + d] = hn;
}

// ---------------- FC: predictions (masked) : 3264x10000, K=512 ----------------
__global__ __launch_bounds__(256)
void fc_kernel(const float* __restrict__ hall, const float* __restrict__ fcW,
               const float* __restrict__ fcb, const int* __restrict__ declen,
               float* __restrict__ out) {
    __shared__ float As[16][66];
    __shared__ float Bs[16][68];
    int tid = threadIdx.x;
    int n0 = blockIdx.x * 64, m0 = blockIdx.y * 64;
    int tx = tid & 15, ty = tid >> 4;
    int lm = tid >> 2, lk4 = (tid & 3) * 4;
    int bkk = tid >> 4, bnn4 = (tid & 15) * 4;
    const float* arow = hall + (size_t)(m0 + lm) * DECD;
    bool nfull = (n0 + 64 <= VOC);
    float acc[4][4] = {};
    for (int k0 = 0; k0 < 512; k0 += 16) {
        float4 av = *(const float4*)(arow + k0 + lk4);
        float4 bv;
        if (nfull) {
            bv = *(const float4*)(fcW + (size_t)(k0 + bkk) * VOC + n0 + bnn4);
        } else {
            const float* bp = fcW + (size_t)(k0 + bkk) * VOC;
            int nb = n0 + bnn4;
            bv.x = (nb + 0 < VOC) ? bp[nb + 0] : 0.f;
            bv.y = (nb + 1 < VOC) ? bp[nb + 1] : 0.f;
            bv.z = (nb + 2 < VOC) ? bp[nb + 2] : 0.f;
            bv.w = (nb + 3 < VOC) ? bp[nb + 3] : 0.f;
        }
        __syncthreads();
        As[lk4 + 0][lm] = av.x; As[lk4 + 1][lm] = av.y;
        As[lk4 + 2][lm] = av.z; As[lk4 + 3][lm] = av.w;
        *(float4*)&Bs[bkk][bnn4] = bv;
        __syncthreads();
#pragma unroll
        for (int kk = 0; kk < 16; kk++) {
            float a[4], bq[4];
#pragma unroll
            for (int i = 0; i < 4; i++) a[i] = As[kk][ty * 4 + i];
#pragma unroll
            for (int jj = 0; jj < 4; jj++) bq[jj] = Bs[kk][tx * 4 + jj];
#pragma unroll
            for (int i = 0; i < 4; i++)
#pragma unroll
                for (int jj = 0; jj < 4; jj++) acc[i][jj] += a[i] * bq[jj];
        }
    }
#pragma unroll
    for (int i = 0; i < 4; i++) {
        int m = m0 + ty * 4 + i;
        int b = m / MAXT, t = m - b * MAXT;
        bool act = t < declen[b];
        int n = n0 + tx * 4;
        if (nfull) {
            float4 o;
            o.x = act ? acc[i][0] + fcb[n + 0] : 0.f;
            o.y = act ? acc[i][1] + fcb[n + 1] : 0.f;
            o.z = act ? acc[i][2] + fcb[n + 2] : 0.f;
            o.w = act ? acc[i][3] + fcb[n + 3] : 0.f;
            *(float4*)(out + (size_t)m * VOC + n) = o;
        } else {
#pragma unroll
            for (int jj = 0; jj < 4; jj++) {
                int nn = n + jj;
                if (nn < VOC) out[(size_t)m * VOC + nn] = act ? acc[i][jj] + fcb[nn] : 0.f;
            }
        }
    }
}

extern "C" void kernel_launch(void* const* d_in, const int* in_sizes, int n_in,
                              void* d_out, int out_size, void* d_ws, size_t ws_size,
                              hipStream_t stream) {
    const float* enc     = (const float*)d_in[0];
    const int*   ecaps   = (const int*)d_in[1];
    const int*   lens    = (const int*)d_in[2];
    const int*   classk  = (const int*)d_in[3];
    const float* embW    = (const float*)d_in[4];
    const float* clsW    = (const float*)d_in[5];
    const float* encattW = (const float*)d_in[6];
    const float* encattb = (const float*)d_in[7];
    const float* decattW = (const float*)d_in[8];
    const float* decattb = (const float*)d_in[9];
    const float* fullw   = (const float*)d_in[10];
    const float* fullb   = (const float*)d_in[11];
    const float* ihW     = (const float*)d_in[12];
    const float* ihb     = (const float*)d_in[13];
    const float* icW     = (const float*)d_in[14];
    const float* icb     = (const float*)d_in[15];
    const float* fbW     = (const float*)d_in[16];
    const float* fbb     = (const float*)d_in[17];
    const float* Wih     = (const float*)d_in[18];
    const float* Whh     = (const float*)d_in[19];
    const float* bih     = (const float*)d_in[20];
    const float* bhh     = (const float*)d_in[21];
    const float* fcW     = (const float*)d_in[22];
    const float* fcb     = (const float*)d_in[23];

    float* out = (float*)d_out;
    float* ws  = (float*)d_ws;
    int*   wsi = (int*)d_ws;

    int*   sortind = wsi + W_SORT;
    int*   declen  = wsi + W_DECLEN;
    int*   caps_i  = wsi + W_CAPS;
    float* cls     = ws + W_CLS;
    float* h       = ws + W_H;
    float* c       = ws + W_C;
    float* initin  = ws + W_ININ;
    float* Z       = ws + W_Z;
    float* awe     = ws + W_AWE;
    float* gates   = ws + W_GATES;
    float* clspre  = ws + W_CLSPRE;
    float* W1      = ws + W_W1;
    float* W2      = ws + W_W2;
    float* hall    = ws + W_HALL;
    float* att1    = ws + W_ATT1;

    setup_kernel<<<1, 64, 0, stream>>>(lens, out, sortind, declen);
    gather_kernel<<<141, 256, 0, stream>>>(ecaps, classk, clsW, sortind, caps_i, cls, out);
    mean_cls_kernel<<<BB, 256, 0, stream>>>(enc, cls, sortind, initin);
    init_hc_kernel<<<256, 256, 0, stream>>>(initin, ihW, ihb, icW, icb, h, c);
    pack_w1_kernel<<<6144, 256, 0, stream>>>(decattW, fbW, Whh, W1);
    pack_w2_kernel<<<8192, 256, 0, stream>>>(Wih, W2);
    att1_kernel<<<dim3(8, 196), 256, 0, stream>>>(enc, encattW, encattb, sortind, att1);
    clspre_kernel<<<32, 256, 0, stream>>>(cls, Wih, bih, bhh, clspre);

    for (int t = 0; t < MAXT; t++) {
        s1_kernel<<<48, 1024, 0, stream>>>(h, W1, decattb, fbb, Z);
        s2_kernel<<<BB, 256, 0, stream>>>(att1, Z, enc, fullw, fullb, sortind, declen, awe, t);
        s3_kernel<<<32, 1024, 0, stream>>>(embW, awe, W2, clspre, Z, caps_i, gates, t);
        s4_kernel<<<128, 256, 0, stream>>>(gates, h, c, hall, declen, t);
    }

    fc_kernel<<<dim3(157, 51), 256, 0, stream>>>(hall, fcW, fcb, declen, out);
}